// Round 1
// baseline (1464.353 us; speedup 1.0000x reference)
//
#include <hip/hip_runtime.h>

// Diffeomorphic transform (scaling & squaring), 7 steps.
// flow: [1, 3, 192, 192, 192] fp32, channel c=0 -> d(z) disp, c=1 -> h(y), c=2 -> w(x).
// Each step: out = f + trilinear_sample(f, voxel + f*(size-1)/2), border clamp,
// align_corners=True (identity grid unnormalizes exactly to voxel index).

constexpr int DD = 192, HH = 192, WW = 192;
constexpr int NN = DD * HH * WW;

__global__ __launch_bounds__(256) void diffeo_step(
    const float* __restrict__ src, float* __restrict__ dst, float scale)
{
    int idx = blockIdx.x * 256 + threadIdx.x;
    if (idx >= NN) return;

    int w = idx % WW;
    int t = idx / WW;
    int h = t % HH;
    int d = t / HH;

    // own (already-scaled-by-caller semantics: raw*scale) displacement
    float f0 = src[idx]          * scale;  // z / depth
    float f1 = src[idx + NN]     * scale;  // y / height
    float f2 = src[idx + 2 * NN] * scale;  // x / width

    // sample position, border-clamped
    float x = fminf(fmaxf((float)w + f2 * (0.5f * (WW - 1)), 0.0f), (float)(WW - 1));
    float y = fminf(fmaxf((float)h + f1 * (0.5f * (HH - 1)), 0.0f), (float)(HH - 1));
    float z = fminf(fmaxf((float)d + f0 * (0.5f * (DD - 1)), 0.0f), (float)(DD - 1));

    int x0 = (int)x;  float wx = x - (float)x0;
    int y0 = (int)y;  float wy = y - (float)y0;
    int z0 = (int)z;  float wz = z - (float)z0;
    int x1 = min(x0 + 1, WW - 1);
    int y1 = min(y0 + 1, HH - 1);
    int z1 = min(z0 + 1, DD - 1);

    float ox = 1.0f - wx, oy = 1.0f - wy, oz = 1.0f - wz;
    float w000 = ox * oy * oz;
    float w001 = wx * oy * oz;
    float w010 = ox * wy * oz;
    float w011 = wx * wy * oz;
    float w100 = ox * oy * wz;
    float w101 = wx * oy * wz;
    float w110 = ox * wy * wz;
    float w111 = wx * wy * wz;

    int b00 = (z0 * HH + y0) * WW;
    int b01 = (z0 * HH + y1) * WW;
    int b10 = (z1 * HH + y0) * WW;
    int b11 = (z1 * HH + y1) * WW;

    float own[3] = {f0, f1, f2};
#pragma unroll
    for (int c = 0; c < 3; ++c) {
        const float* s = src + c * NN;
        float v =
            w000 * s[b00 + x0] + w001 * s[b00 + x1] +
            w010 * s[b01 + x0] + w011 * s[b01 + x1] +
            w100 * s[b10 + x0] + w101 * s[b10 + x1] +
            w110 * s[b11 + x0] + w111 * s[b11 + x1];
        dst[idx + c * NN] = own[c] + scale * v;
    }
}

extern "C" void kernel_launch(void* const* d_in, const int* in_sizes, int n_in,
                              void* d_out, int out_size, void* d_ws, size_t ws_size,
                              hipStream_t stream) {
    const float* in = (const float*)d_in[0];
    float* out = (float*)d_out;
    float* ws  = (float*)d_ws;

    const int blocks = (NN + 255) / 256;
    const float inv = 1.0f / 128.0f;  // 2^-TIME_STEP, TIME_STEP=7

    // 7 steps, ping-pong so the final result lands in d_out:
    // in -> out -> ws -> out -> ws -> out -> ws -> out
    diffeo_step<<<blocks, 256, 0, stream>>>(in,  out, inv);   // it1 (scales input)
    diffeo_step<<<blocks, 256, 0, stream>>>(out, ws,  1.0f);  // it2
    diffeo_step<<<blocks, 256, 0, stream>>>(ws,  out, 1.0f);  // it3
    diffeo_step<<<blocks, 256, 0, stream>>>(out, ws,  1.0f);  // it4
    diffeo_step<<<blocks, 256, 0, stream>>>(ws,  out, 1.0f);  // it5
    diffeo_step<<<blocks, 256, 0, stream>>>(out, ws,  1.0f);  // it6
    diffeo_step<<<blocks, 256, 0, stream>>>(ws,  out, 1.0f);  // it7
}

// Round 2
// 1396.891 us; speedup vs baseline: 1.0483x; 1.0483x over previous
//
#include <hip/hip_runtime.h>

// Diffeomorphic transform (scaling & squaring), 7 steps.
// flow: [1, 3, 192, 192, 192] fp32, c=0 -> z disp, c=1 -> y, c=2 -> x.
// Each step: out = f + trilinear_sample(f, voxel + f*(size-1)/2), border clamp,
// align_corners=True (identity grid unnormalizes exactly to voxel index).
//
// R2: XCD-aware block swizzle. R1 showed FETCH_SIZE ~617 MB/dispatch vs 85 MB
// ideal (7.3x ~= 8 XCDs): round-robin block->XCD mapping means every halo line
// is fetched once per XCD. Give each XCD a contiguous z-chunk instead.

constexpr int DD = 192, HH = 192, WW = 192;
constexpr int NN = DD * HH * WW;
constexpr int NB = NN / 256;      // 27648 blocks
constexpr int NXCD = 8;
constexpr int CHUNK = NB / NXCD;  // 3456 (exact -> bijective swizzle)

__global__ __launch_bounds__(256) void diffeo_step(
    const float* __restrict__ src, float* __restrict__ dst, float scale)
{
    // XCD swizzle: consecutive hardware blocks round-robin XCDs; make XCD k
    // own blocks [k*CHUNK, (k+1)*CHUNK) of the logical (z-major) order.
    int bid = blockIdx.x;
    int swz = (bid & (NXCD - 1)) * CHUNK + (bid >> 3);
    int idx = swz * 256 + threadIdx.x;

    int w = idx % WW;
    int t = idx / WW;
    int h = t % HH;
    int d = t / HH;

    float f0 = src[idx]          * scale;  // z / depth
    float f1 = src[idx + NN]     * scale;  // y / height
    float f2 = src[idx + 2 * NN] * scale;  // x / width

    float x = fminf(fmaxf((float)w + f2 * (0.5f * (WW - 1)), 0.0f), (float)(WW - 1));
    float y = fminf(fmaxf((float)h + f1 * (0.5f * (HH - 1)), 0.0f), (float)(HH - 1));
    float z = fminf(fmaxf((float)d + f0 * (0.5f * (DD - 1)), 0.0f), (float)(DD - 1));

    int x0 = (int)x;  float wx = x - (float)x0;
    int y0 = (int)y;  float wy = y - (float)y0;
    int z0 = (int)z;  float wz = z - (float)z0;
    int x1 = min(x0 + 1, WW - 1);
    int y1 = min(y0 + 1, HH - 1);
    int z1 = min(z0 + 1, DD - 1);

    float ox = 1.0f - wx, oy = 1.0f - wy, oz = 1.0f - wz;
    float w000 = ox * oy * oz;
    float w001 = wx * oy * oz;
    float w010 = ox * wy * oz;
    float w011 = wx * wy * oz;
    float w100 = ox * oy * wz;
    float w101 = wx * oy * wz;
    float w110 = ox * wy * wz;
    float w111 = wx * wy * wz;

    int b00 = (z0 * HH + y0) * WW;
    int b01 = (z0 * HH + y1) * WW;
    int b10 = (z1 * HH + y0) * WW;
    int b11 = (z1 * HH + y1) * WW;

    float own[3] = {f0, f1, f2};
#pragma unroll
    for (int c = 0; c < 3; ++c) {
        const float* s = src + c * NN;
        float v =
            w000 * s[b00 + x0] + w001 * s[b00 + x1] +
            w010 * s[b01 + x0] + w011 * s[b01 + x1] +
            w100 * s[b10 + x0] + w101 * s[b10 + x1] +
            w110 * s[b11 + x0] + w111 * s[b11 + x1];
        dst[idx + c * NN] = own[c] + scale * v;
    }
}

extern "C" void kernel_launch(void* const* d_in, const int* in_sizes, int n_in,
                              void* d_out, int out_size, void* d_ws, size_t ws_size,
                              hipStream_t stream) {
    const float* in = (const float*)d_in[0];
    float* out = (float*)d_out;
    float* ws  = (float*)d_ws;

    const float inv = 1.0f / 128.0f;  // 2^-TIME_STEP, TIME_STEP=7

    // 7 steps, ping-pong so the final result lands in d_out:
    diffeo_step<<<NB, 256, 0, stream>>>(in,  out, inv);   // it1 (scales input)
    diffeo_step<<<NB, 256, 0, stream>>>(out, ws,  1.0f);  // it2
    diffeo_step<<<NB, 256, 0, stream>>>(ws,  out, 1.0f);  // it3
    diffeo_step<<<NB, 256, 0, stream>>>(out, ws,  1.0f);  // it4
    diffeo_step<<<NB, 256, 0, stream>>>(ws,  out, 1.0f);  // it5
    diffeo_step<<<NB, 256, 0, stream>>>(out, ws,  1.0f);  // it6
    diffeo_step<<<NB, 256, 0, stream>>>(ws,  out, 1.0f);  // it7
}

// Round 3
// 985.984 us; speedup vs baseline: 1.4852x; 1.4167x over previous
//
#include <hip/hip_runtime.h>

// Diffeomorphic transform (scaling & squaring), 7 steps.
// flow: [1, 3, 192, 192, 192] fp32, c=0 -> z disp, c=1 -> y, c=2 -> x.
// Each step: out = f + trilinear_sample(f, voxel + f*(size-1)/2), border clamp,
// align_corners=True (identity grid unnormalizes exactly to voxel index).
//
// R2: XCD swizzle (kept). R3: store intermediates channel-INTERLEAVED so each
// trilinear corner reads 3 contiguous floats (12B) instead of 3 locations
// 28MB apart -> 4 scattered row-segments per voxel instead of 12. Late
// iterations gather with large, rough displacements and are line-fetch bound.

constexpr int DD = 192, HH = 192, WW = 192;
constexpr int NN = DD * HH * WW;
constexpr int NB = NN / 256;      // 27648 blocks
constexpr int NXCD = 8;
constexpr int CHUNK = NB / NXCD;  // 3456 (exact -> bijective swizzle)

// SES/SCS: source element/channel stride; DES/DCS: dest. Planar: (1, NN).
// Interleaved: (3, 1).
template <int SES, int SCS, int DES, int DCS>
__global__ __launch_bounds__(256) void diffeo_step(
    const float* __restrict__ src, float* __restrict__ dst, float scale)
{
    int bid = blockIdx.x;
    int swz = (bid & (NXCD - 1)) * CHUNK + (bid >> 3);
    int idx = swz * 256 + threadIdx.x;

    int w = idx % WW;
    int t = idx / WW;
    int h = t % HH;
    int d = t / HH;

    float f0 = src[idx * SES + 0 * SCS] * scale;  // z / depth
    float f1 = src[idx * SES + 1 * SCS] * scale;  // y / height
    float f2 = src[idx * SES + 2 * SCS] * scale;  // x / width

    float x = fminf(fmaxf((float)w + f2 * (0.5f * (WW - 1)), 0.0f), (float)(WW - 1));
    float y = fminf(fmaxf((float)h + f1 * (0.5f * (HH - 1)), 0.0f), (float)(HH - 1));
    float z = fminf(fmaxf((float)d + f0 * (0.5f * (DD - 1)), 0.0f), (float)(DD - 1));

    int x0 = (int)x;  float wx = x - (float)x0;
    int y0 = (int)y;  float wy = y - (float)y0;
    int z0 = (int)z;  float wz = z - (float)z0;
    int x1 = min(x0 + 1, WW - 1);
    int y1 = min(y0 + 1, HH - 1);
    int z1 = min(z0 + 1, DD - 1);

    float ox = 1.0f - wx, oy = 1.0f - wy, oz = 1.0f - wz;
    float w000 = ox * oy * oz;
    float w001 = wx * oy * oz;
    float w010 = ox * wy * oz;
    float w011 = wx * wy * oz;
    float w100 = ox * oy * wz;
    float w101 = wx * oy * wz;
    float w110 = ox * wy * wz;
    float w111 = wx * wy * wz;

    int p000 = ((z0 * HH + y0) * WW + x0) * SES;
    int p001 = ((z0 * HH + y0) * WW + x1) * SES;
    int p010 = ((z0 * HH + y1) * WW + x0) * SES;
    int p011 = ((z0 * HH + y1) * WW + x1) * SES;
    int p100 = ((z1 * HH + y0) * WW + x0) * SES;
    int p101 = ((z1 * HH + y0) * WW + x1) * SES;
    int p110 = ((z1 * HH + y1) * WW + x0) * SES;
    int p111 = ((z1 * HH + y1) * WW + x1) * SES;

    float own[3] = {f0, f1, f2};
#pragma unroll
    for (int c = 0; c < 3; ++c) {
        const float* s = src + c * SCS;
        float v =
            w000 * s[p000] + w001 * s[p001] +
            w010 * s[p010] + w011 * s[p011] +
            w100 * s[p100] + w101 * s[p101] +
            w110 * s[p110] + w111 * s[p111];
        dst[idx * DES + c * DCS] = own[c] + scale * v;
    }
}

extern "C" void kernel_launch(void* const* d_in, const int* in_sizes, int n_in,
                              void* d_out, int out_size, void* d_ws, size_t ws_size,
                              hipStream_t stream) {
    const float* in = (const float*)d_in[0];
    float* out = (float*)d_out;
    float* ws  = (float*)d_ws;

    const float inv = 1.0f / 128.0f;  // 2^-TIME_STEP, TIME_STEP=7

    // Layouts: input planar (1, NN); intermediates interleaved (3, 1);
    // final output planar. Ping-pong: in->out->ws->out->ws->out->ws->out.
    diffeo_step<1, NN, 3, 1><<<NB, 256, 0, stream>>>(in,  out, inv);   // it1
    diffeo_step<3, 1,  3, 1><<<NB, 256, 0, stream>>>(out, ws,  1.0f);  // it2
    diffeo_step<3, 1,  3, 1><<<NB, 256, 0, stream>>>(ws,  out, 1.0f);  // it3
    diffeo_step<3, 1,  3, 1><<<NB, 256, 0, stream>>>(out, ws,  1.0f);  // it4
    diffeo_step<3, 1,  3, 1><<<NB, 256, 0, stream>>>(ws,  out, 1.0f);  // it5
    diffeo_step<3, 1,  3, 1><<<NB, 256, 0, stream>>>(out, ws,  1.0f);  // it6
    diffeo_step<3, 1,  1, NN><<<NB, 256, 0, stream>>>(ws,  out, 1.0f); // it7
}